// Round 1
// baseline (718.794 us; speedup 1.0000x reference)
//
#include <hip/hip_runtime.h>

// B=2, T=12, C=128, H=W=32, heads=4, dh=32, layers=5. fp32 I/O.
// Algebra: key-axis softmax cancels q-conv & att_b; attention weights are
// query-independent (head output broadcast over the 12 frames).
// Layout: channels-last fp32 activations [img][1024px][128c] + padded bf16
// copies A2[img][34*34 pos][128c] so conv MFMA A-fragments are direct
// contiguous global loads (no LDS in the convs).
// This round: (1) conv address math hoisted to k-invariant 32-bit lane
// offsets + wave-uniform per-tap base (saddr form, kills per-k 64-bit VALU
// chains); (2) k_attn computes 4 x-adjacent px/thread with ci split across
// waves (2x fewer LDS insts); (3) prep kernels fused into one dispatch.
#define NELEM 3145728
#define IMG 24
#define CH 128
#define HW 1024
#define PADP 1156          // 34*34
#define A2IMG 147968       // 1156*128

using short8  = __attribute__((ext_vector_type(8))) short;
using float4v = __attribute__((ext_vector_type(4))) float;

__device__ inline unsigned short f2bf(float f){
    union { float f; unsigned u; } c; c.f = f;
    return (unsigned short)((c.u + 0x7FFF + ((c.u >> 16) & 1)) >> 16);
}
__device__ inline float bf2f(unsigned short h){
    union { unsigned u; float f; } c; c.u = ((unsigned)h) << 16; return c.f;
}

// ---------------- fused prep: weight transforms + A2 borders + init ----------------
// [0,1474560)           : ff1/ff2 fp32 -> bf16 MFMA-B layout
// [1474560,1658880)     : kv  fp32 -> bf16 MFMA-B layout (grouped)
// [1658880,2469888)     : zero padded borders of A2a/A2v
// [2469888,3256320)     : NCHW fp32 input -> CL cur fp32 + A2a bf16 interior
__global__ __launch_bounds__(256) void k_prep(
    const float* __restrict__ ff1w, const float* __restrict__ ff2w,
    const float* __restrict__ kvw, const float* __restrict__ input,
    unsigned short* __restrict__ Wd, unsigned short* __restrict__ Wkv,
    unsigned short* __restrict__ A2a, unsigned short* __restrict__ A2v,
    float* __restrict__ cur)
{
    int gid = blockIdx.x * 256 + threadIdx.x;        // 12720*256 = 3256320 exact
    if (gid < 1474560) {
        int idx = gid;
        int li2 = idx / 147456, r1 = idx - li2 * 147456;
        int j = r1 & 7, t16 = r1 >> 3;
        int co = t16 & 127, tcq = t16 >> 7;
        int quad = tcq & 3, cc = (tcq >> 2) & 3, tap = tcq >> 4;
        const float* base = ((li2 & 1) ? ff2w : ff1w) + (size_t)(li2 >> 1) * 147456;
        Wd[idx] = f2bf(base[(co * 128 + cc * 32 + quad * 8 + j) * 9 + tap]);
    } else if (gid < 1658880) {
        int idx = gid - 1474560;
        int li = idx / 36864, r1 = idx - li * 36864;
        int j = r1 & 7, t16 = r1 >> 3;
        int co = t16 & 127, tq = t16 >> 7;
        int quad = tq & 3, tap = tq >> 2;
        int h = co >> 5, col = co & 31;
        Wkv[idx] = f2bf(kvw[(size_t)(((li * 4 + h) * 32 + col) * 32 + quad * 8 + j) * 9 + tap]);
    } else if (gid < 2469888) {
        int g2 = gid - 1658880;                      // 2*24*132*128
        int c = g2 & 127, r = g2 >> 7;
        int bp = r % 132, r2 = r / 132;
        int img = r2 % 24, buf = r2 / 24;
        int pos;
        if (bp < 34) pos = bp;
        else if (bp < 68) pos = 33 * 34 + (bp - 34);
        else if (bp < 100) pos = (bp - 68 + 1) * 34;
        else pos = (bp - 100 + 1) * 34 + 33;
        unsigned short* p = buf ? A2v : A2a;
        p[(size_t)img * A2IMG + pos * 128 + c] = 0;
    } else {
        int g2 = gid - 2469888;                      // 24*1024*32
        int c4 = (g2 & 31) * 4, px = (g2 >> 5) & 1023, img = g2 >> 15;
        float4v v;
        #pragma unroll
        for (int j = 0; j < 4; j++)
            v[j] = input[((size_t)img * 128 + c4 + j) * HW + px];
        *(float4v*)(cur + ((size_t)img * HW + px) * 128 + c4) = v;
        int pos = ((px >> 5) + 1) * 34 + (px & 31) + 1;
        unsigned short* ap = A2a + ((size_t)img * PADP + pos) * 128 + c4;
        #pragma unroll
        for (int j = 0; j < 4; j++) ap[j] = f2bf(v[j]);
    }
}

// ---------------- implicit-GEMM 3x3 conv, channels-last, no LDS ----------------
// grid (8 rq, 24 img, 2 zc). Block 256 = 4 waves, wave grid 2m x 2n.
// Block tile 128px(4 rows) x 64co. Wave: 4 m-frags(16px) x 2 n-frags(16co).
// A: saddr-form loads: wave-uniform per-tap base + k-invariant 32-bit lane
// offsets (aoff[mt]); B: uniform per-k pointer bump + fixed lane offset.
template<bool GROUPED, bool RELU, bool RES, bool EF32, bool EA2, bool STAT>
__global__ __launch_bounds__(256) void k_conv(
    const unsigned short* __restrict__ a2in, const unsigned short* __restrict__ w2,
    const float* __restrict__ bias, const float* __restrict__ res,
    float* __restrict__ outf, unsigned short* __restrict__ outa2,
    float* __restrict__ pstat)
{
    const int y0 = blockIdx.x * 4;
    const int img = blockIdx.y;
    const int zc = blockIdx.z;
    const int t = threadIdx.x;
    const int wave = t >> 6, lane = t & 63;
    const int wm = wave & 1, wn = wave >> 1;
    const int n16 = lane & 15, quad = lane >> 4;
    const int cog = zc * 64 + wn * 32;          // wave's co base
    const int head = zc * 2 + wn;               // co group (grouped head / GN group)

    const short8* w8 = reinterpret_cast<const short8*>(w2);
    const unsigned short* abase = a2in + (size_t)img * A2IMG + (GROUPED ? head * 32 : 0);

    constexpr int NK = GROUPED ? 9 : 36;

    // k-invariant per-lane offsets (elements)
    int aoff[4];
    #pragma unroll
    for (int mt = 0; mt < 4; mt++) {
        int y = y0 + wm * 2 + (mt >> 1);
        aoff[mt] = (y * 34 + (mt & 1) * 16 + n16) * 128 + quad * 8;
    }
    const int boff = quad * 128 + cog + n16;    // short8-element index

    float4v acc[4][2];
    #pragma unroll
    for (int a = 0; a < 4; a++)
        #pragma unroll
        for (int b = 0; b < 2; b++) acc[a][b] = (float4v){0.f,0.f,0.f,0.f};

    short8 af[3][4], bf[3][2];

    auto loadA = [&](int k, int s){
        const int tap = GROUPED ? k : (k >> 2);
        const int cc  = GROUPED ? 0 : (k & 3);
        const int ky = tap / 3, kx = tap - ky * 3;
        const unsigned short* ab = abase + (ky * 34 + kx) * 128 + cc * 32; // uniform
        #pragma unroll
        for (int mt = 0; mt < 4; mt++)
            af[s][mt] = *reinterpret_cast<const short8*>(ab + aoff[mt]);
    };
    auto loadB = [&](int k, int s){
        const short8* wk = w8 + k * 512;                                  // uniform
        #pragma unroll
        for (int nt = 0; nt < 2; nt++)
            bf[s][nt] = wk[boff + nt * 16];
    };

    #pragma unroll
    for (int k = 0; k < 3; k++) { loadA(k, k); loadB(k, k); }
    #pragma unroll
    for (int k = 0; k < NK; k++) {
        const int s = k % 3;
        #pragma unroll
        for (int mt = 0; mt < 4; mt++)
            #pragma unroll
            for (int nt = 0; nt < 2; nt++)
                acc[mt][nt] = __builtin_amdgcn_mfma_f32_16x16x32_bf16(
                    af[s][mt], bf[s][nt], acc[mt][nt], 0, 0, 0);
        if (k + 3 < NK) { loadA(k + 3, s); loadB(k + 3, s); }
    }

    // epilogue: D col = n16 (co offset), row = quad*4+reg (x offset)
    float s1 = 0.f, s2 = 0.f;
    #pragma unroll
    for (int mt = 0; mt < 4; mt++) {
        int y = y0 + wm * 2 + (mt >> 1);
        int xb = (mt & 1) * 16 + quad * 4;
        #pragma unroll
        for (int nt = 0; nt < 2; nt++) {
            int co = cog + nt * 16 + n16;
            float bb = bias[co];
            #pragma unroll
            for (int r = 0; r < 4; r++) {
                int px = y * 32 + xb + r;
                float val = acc[mt][nt][r] + bb;
                if (RELU) val = fmaxf(val, 0.f);
                size_t ci = ((size_t)img * HW + px) * 128 + co;
                if (RES) val += res[ci];
                if (EF32) outf[ci] = val;
                if (EA2) {
                    int pos = (y + 1) * 34 + xb + r + 1;
                    outa2[((size_t)img * PADP + pos) * 128 + co] = f2bf(val);
                }
                if (STAT) { s1 += val; s2 += val * val; }
            }
        }
    }
    if (STAT) {
        #pragma unroll
        for (int o = 32; o > 0; o >>= 1) {
            s1 += __shfl_down(s1, o); s2 += __shfl_down(s2, o);
        }
        if (lane == 0) {
            atomicAdd(&pstat[(img * 4 + head) * 2], s1);
            atomicAdd(&pstat[(img * 4 + head) * 2 + 1], s2);
        }
    }
}

// ---------------- attention logit conv (reads padded bf16 A2v) ----------------
// 4 x-adjacent outputs per thread; 32 ci split across the 4 waves (8 each),
// LDS tree-reduce at the end. Row stride 35 / plane stride 353 keeps ~2-way
// bank aliasing (free) on both stage writes and compute reads.
__global__ __launch_bounds__(256) void k_attn(
    const unsigned short* __restrict__ a2v, const float* __restrict__ aw,
    float* __restrict__ ak, float* __restrict__ pstat)
{
    const int img = blockIdx.x;            // b*12 + l
    const int h = blockIdx.y;
    const int y0 = blockIdx.z * 8;
    const int t = threadIdx.x;
    const int b = img / 12, l = img - b * 12;

    if (blockIdx.x == 0 && blockIdx.y == 0 && blockIdx.z == 0 && t < 192)
        pstat[t] = 0.f;                     // zero GN stats for this layer's ff2

    __shared__ float sxv[32 * 353];         // ci-major: plane 353, row 35
    __shared__ float4v sred[4][64];
    __shared__ float spos[32];
    if (t < 32) {
        int j2 = t & ~1;
        float freq = __expf(-(float)j2 * 0.28782313662425576f);
        float ang = (float)l * freq;
        spos[t] = (t & 1) ? __cosf(ang) : __sinf(ang);
    }
    __syncthreads();

    // stage 10 padded rows x 34 cols x 32 ci, add pos on interior
    const unsigned short* vb = a2v + (size_t)img * A2IMG + h * 32;
    for (int idx = t; idx < 1360; idx += 256) {
        int q = idx & 3, pos = idx >> 2;
        int lr = pos / 34, lc = pos - lr * 34;
        int row = y0 + lr;
        bool inter = (row >= 1 && row <= 32 && lc >= 1 && lc <= 32);
        short8 vv = *reinterpret_cast<const short8*>(vb + (size_t)(y0 * 34 + pos) * 128 + q * 8);
        #pragma unroll
        for (int j = 0; j < 8; j++) {
            float f = bf2f((unsigned short)vv[j]);
            if (inter) f += spos[q * 8 + j];
            sxv[(q * 8 + j) * 353 + lr * 35 + lc] = f;
        }
    }
    __syncthreads();

    const int cig = t >> 6, u = t & 63;     // cig = wave id -> uniform weights
    const int r = u >> 3, x0 = (u & 7) * 4;
    const float* wb = aw + (h * 64 + 32) * 9 + cig * 72;  // K-half weights
    float4v acc = (float4v){0.f,0.f,0.f,0.f};
    #pragma unroll
    for (int ci = 0; ci < 8; ci++) {
        const float* sp = sxv + (cig * 8 + ci) * 353 + r * 35 + x0;
        const float* wp = wb + ci * 9;
        #pragma unroll
        for (int ky = 0; ky < 3; ky++) {
            float f0 = sp[ky*35+0], f1 = sp[ky*35+1], f2 = sp[ky*35+2];
            float f3 = sp[ky*35+3], f4 = sp[ky*35+4], f5 = sp[ky*35+5];
            float w0 = wp[ky*3+0], w1 = wp[ky*3+1], w2f = wp[ky*3+2];
            acc[0] = fmaf(f2, w2f, fmaf(f1, w1, fmaf(f0, w0, acc[0])));
            acc[1] = fmaf(f3, w2f, fmaf(f2, w1, fmaf(f1, w0, acc[1])));
            acc[2] = fmaf(f4, w2f, fmaf(f3, w1, fmaf(f2, w0, acc[2])));
            acc[3] = fmaf(f5, w2f, fmaf(f4, w1, fmaf(f3, w0, acc[3])));
        }
    }
    sred[cig][u] = acc;
    __syncthreads();
    if (t < 64) {
        float4v s = sred[0][t];
        #pragma unroll
        for (int g = 1; g < 4; g++) {
            float4v o = sred[g][t];
            #pragma unroll
            for (int j = 0; j < 4; j++) s[j] += o[j];
        }
        int rr = t >> 3, xx0 = (t & 7) * 4;
        *reinterpret_cast<float4v*>(ak + ((size_t)((b * 4 + h) * 12 + l) * HW)
                                    + (y0 + rr) * 32 + xx0) = s;
    }
}

// ---------------- fused softmax + weighted sum + residual (+A2a emit) ----------------
__global__ __launch_bounds__(256) void k_wsum(const float* __restrict__ ak,
    const float* __restrict__ v, float* __restrict__ cur,
    unsigned short* __restrict__ a2a)
{
    int gid = blockIdx.x * 256 + threadIdx.x;   // 2*1024*32
    int c4 = (gid & 31) * 4, px = (gid >> 5) & 1023, b = gid >> 15;
    int h = c4 >> 5;
    const float* wp = ak + ((b * 4 + h) * 12) * HW + px;
    float a[12], m = -1e30f;
    #pragma unroll
    for (int l = 0; l < 12; l++) { a[l] = wp[l * HW]; m = fmaxf(m, a[l]); }
    float ssum = 0.f;
    #pragma unroll
    for (int l = 0; l < 12; l++) { a[l] = __expf(a[l] - m); ssum += a[l]; }
    float invs = 1.f / ssum;
    float4v s = (float4v){0.f,0.f,0.f,0.f};
    #pragma unroll
    for (int l = 0; l < 12; l++) {
        float4v vv = *(const float4v*)(v + (((size_t)(b * 12 + l) * HW) + px) * 128 + c4);
        #pragma unroll
        for (int j = 0; j < 4; j++) s[j] += a[l] * vv[j];
    }
    #pragma unroll
    for (int j = 0; j < 4; j++) s[j] *= invs;
    int pos = ((px >> 5) + 1) * 34 + (px & 31) + 1;
    #pragma unroll
    for (int l = 0; l < 12; l++) {
        size_t ci = (((size_t)(b * 12 + l) * HW) + px) * 128 + c4;
        float4v cv = *(float4v*)(cur + ci);
        #pragma unroll
        for (int j = 0; j < 4; j++) cv[j] += s[j];
        *(float4v*)(cur + ci) = cv;
        unsigned short* ap = a2a + ((size_t)(b * 12 + l) * PADP + pos) * 128 + c4;
        #pragma unroll
        for (int j = 0; j < 4; j++) ap[j] = f2bf(cv[j]);
    }
}

// ---------------- GroupNorm finalize+apply (in-place on cur / final NCHW) ----------------
template<bool LAST>
__global__ __launch_bounds__(256) void k_gnapply(const float* __restrict__ y,
    const float* __restrict__ pstat, const float* __restrict__ gw,
    const float* __restrict__ gb, float* __restrict__ cur,
    unsigned short* __restrict__ a2a, float* __restrict__ outp)
{
    int gid = blockIdx.x * 256 + threadIdx.x;   // 24*1024*32
    if (!LAST) {
        int c4 = (gid & 31) * 4, px = (gid >> 5) & 1023, img = gid >> 15;
        int g = c4 >> 5;
        float S = pstat[(img * 4 + g) * 2], Q = pstat[(img * 4 + g) * 2 + 1];
        float mu = S * (1.f / 32768.f);
        float inv = rsqrtf(Q * (1.f / 32768.f) - mu * mu + 1e-5f);
        float4v vv = *(const float4v*)(y + ((size_t)img * HW + px) * 128 + c4);
        int pos = ((px >> 5) + 1) * 34 + (px & 31) + 1;
        size_t ci = ((size_t)img * HW + px) * 128 + c4;
        unsigned short* ap = a2a + ((size_t)img * PADP + pos) * 128 + c4;
        #pragma unroll
        for (int j = 0; j < 4; j++) {
            float val = (vv[j] - mu) * inv * gw[c4 + j] + gb[c4 + j];
            vv[j] = val;
            ap[j] = f2bf(val);
        }
        *(float4v*)(cur + ci) = vv;
    } else {
        int px4 = (gid & 255) * 4, c = (gid >> 8) & 127, img = gid >> 15;
        int g = c >> 5;
        float S = pstat[(img * 4 + g) * 2], Q = pstat[(img * 4 + g) * 2 + 1];
        float mu = S * (1.f / 32768.f);
        float inv = rsqrtf(Q * (1.f / 32768.f) - mu * mu + 1e-5f);
        float gg = gw[c], bb = gb[c];
        float4v o;
        #pragma unroll
        for (int j = 0; j < 4; j++) {
            float val = y[((size_t)img * HW + px4 + j) * 128 + c];
            o[j] = (val - mu) * inv * gg + bb;
        }
        *(float4v*)(outp + ((size_t)img * 128 + c) * HW + px4) = o;
    }
}

extern "C" void kernel_launch(void* const* d_in, const int* in_sizes, int n_in,
                              void* d_out, int out_size, void* d_ws, size_t ws_size,
                              hipStream_t stream)
{
    const float* input = (const float*)d_in[0];
    // d_in[1] q_w, d_in[2] q_b, d_in[6] att_b cancel in key-axis softmax.
    const float* kv_w  = (const float*)d_in[3];
    const float* kv_b  = (const float*)d_in[4];
    const float* att_w = (const float*)d_in[5];
    const float* ff1_w = (const float*)d_in[7];
    const float* ff1_b = (const float*)d_in[8];
    const float* ff2_w = (const float*)d_in[9];
    const float* ff2_b = (const float*)d_in[10];
    const float* gn_w  = (const float*)d_in[11];
    const float* gn_b  = (const float*)d_in[12];

    // ws layout (~30.5 MB): no buffer aliases another live buffer.
    float* ws  = (float*)d_ws;
    float* cur = ws;                          // CL fp32 (24,1024,128)
    float* ak  = ws + (size_t)NELEM;          // 98304
    float* pstat = ak + 98304;                // 192
    unsigned short* W2d  = (unsigned short*)(pstat + 192);   // 1,474,560
    unsigned short* W2kv = W2d + 1474560;                    // 184,320
    unsigned short* A2v  = W2kv + 184320;                    // 24*147968
    unsigned short* A2a  = A2v + (size_t)IMG * A2IMG;        // 24*147968
    // d_out doubles as the fp32 v buffer (dead before the final output write).
    float* v    = (float*)d_out;
    float* outp = (float*)d_out;

    k_prep<<<12720, 256, 0, stream>>>(ff1_w, ff2_w, kv_w, input,
                                      W2d, W2kv, A2a, A2v, cur);

    for (int li = 0; li < 5; li++) {
        // v (d_out) = grouped conv(A2a) + kv_b ; also emit A2v bf16
        k_conv<true, false, false, true, true, false><<<dim3(8, IMG, 2), 256, 0, stream>>>(
            A2a, W2kv + (size_t)li * 36864, kv_b + li * 128, nullptr, v, A2v, nullptr);
        // attention logits from k = v + pos (also zeroes pstat for this layer)
        k_attn<<<dim3(IMG, 4, 4), 256, 0, stream>>>(A2v, att_w + (size_t)li * 2304, ak, pstat);
        // cur += softmax-weighted sum of v (broadcast over frames); emit A2a
        k_wsum<<<256, 256, 0, stream>>>(ak, v, cur, A2a);
        // f1 = relu(conv(A2a, ff1)) -> A2v only
        k_conv<false, true, false, false, true, false><<<dim3(8, IMG, 2), 256, 0, stream>>>(
            A2a, W2d + (size_t)(li * 2 + 0) * 147456, ff1_b + li * 128, nullptr, nullptr, A2v, nullptr);
        // cur = conv(A2v, ff2) + cur  (in-place, element-wise) + GN partial stats
        k_conv<false, false, true, true, false, true><<<dim3(8, IMG, 2), 256, 0, stream>>>(
            A2v, W2d + (size_t)(li * 2 + 1) * 147456, ff2_b + li * 128, cur, cur, nullptr, pstat);
        // GN apply: in-place on cur + A2a emit, or final NCHW transpose to d_out
        if (li == 4)
            k_gnapply<true><<<3072, 256, 0, stream>>>(cur, pstat, gn_w + li * 128,
                gn_b + li * 128, nullptr, nullptr, outp);
        else
            k_gnapply<false><<<3072, 256, 0, stream>>>(cur, pstat, gn_w + li * 128,
                gn_b + li * 128, cur, A2a, nullptr);
    }
}

// Round 2
// 702.820 us; speedup vs baseline: 1.0227x; 1.0227x over previous
//
#include <hip/hip_runtime.h>

// B=2, T=12, C=128, H=W=32, heads=4, dh=32, layers=5. fp32 I/O.
// Algebra: key-axis softmax cancels q-conv & att_b; attention weights are
// query-independent (head output broadcast over the 12 frames).
// Layout: channels-last fp32 activations [img][1024px][128c] + padded bf16
// copies A2[img][34*34 pos][128c] so conv MFMA A-fragments are direct
// contiguous global loads (no LDS in the convs).
// Round 2: convs were latency-bound (MfmaUtil 5.4%, Occ 11.6%, 6 waves/CU).
// Re-tiled to 64px x 64co blocks, grid (16,24,2) = 768 blocks = 12 waves/CU,
// prefetch depth 4, launch_bounds(256,4) caps VGPR<=128 for 4 waves/SIMD.
// k_attn reverted to round-0 form (round-1 rewrite unverified).
#define NELEM 3145728
#define IMG 24
#define CH 128
#define HW 1024
#define PADP 1156          // 34*34
#define A2IMG 147968       // 1156*128

using short8  = __attribute__((ext_vector_type(8))) short;
using float4v = __attribute__((ext_vector_type(4))) float;

__device__ inline unsigned short f2bf(float f){
    union { float f; unsigned u; } c; c.f = f;
    return (unsigned short)((c.u + 0x7FFF + ((c.u >> 16) & 1)) >> 16);
}
__device__ inline float bf2f(unsigned short h){
    union { unsigned u; float f; } c; c.u = ((unsigned)h) << 16; return c.f;
}

// ---------------- fused prep: weight transforms + A2 borders + init ----------------
__global__ __launch_bounds__(256) void k_prep(
    const float* __restrict__ ff1w, const float* __restrict__ ff2w,
    const float* __restrict__ kvw, const float* __restrict__ input,
    unsigned short* __restrict__ Wd, unsigned short* __restrict__ Wkv,
    unsigned short* __restrict__ A2a, unsigned short* __restrict__ A2v,
    float* __restrict__ cur)
{
    int gid = blockIdx.x * 256 + threadIdx.x;        // 12720*256 = 3256320 exact
    if (gid < 1474560) {
        int idx = gid;
        int li2 = idx / 147456, r1 = idx - li2 * 147456;
        int j = r1 & 7, t16 = r1 >> 3;
        int co = t16 & 127, tcq = t16 >> 7;
        int quad = tcq & 3, cc = (tcq >> 2) & 3, tap = tcq >> 4;
        const float* base = ((li2 & 1) ? ff2w : ff1w) + (size_t)(li2 >> 1) * 147456;
        Wd[idx] = f2bf(base[(co * 128 + cc * 32 + quad * 8 + j) * 9 + tap]);
    } else if (gid < 1658880) {
        int idx = gid - 1474560;
        int li = idx / 36864, r1 = idx - li * 36864;
        int j = r1 & 7, t16 = r1 >> 3;
        int co = t16 & 127, tq = t16 >> 7;
        int quad = tq & 3, tap = tq >> 2;
        int h = co >> 5, col = co & 31;
        Wkv[idx] = f2bf(kvw[(size_t)(((li * 4 + h) * 32 + col) * 32 + quad * 8 + j) * 9 + tap]);
    } else if (gid < 2469888) {
        int g2 = gid - 1658880;                      // 2*24*132*128
        int c = g2 & 127, r = g2 >> 7;
        int bp = r % 132, r2 = r / 132;
        int img = r2 % 24, buf = r2 / 24;
        int pos;
        if (bp < 34) pos = bp;
        else if (bp < 68) pos = 33 * 34 + (bp - 34);
        else if (bp < 100) pos = (bp - 68 + 1) * 34;
        else pos = (bp - 100 + 1) * 34 + 33;
        unsigned short* p = buf ? A2v : A2a;
        p[(size_t)img * A2IMG + pos * 128 + c] = 0;
    } else {
        int g2 = gid - 2469888;                      // 24*1024*32
        int c4 = (g2 & 31) * 4, px = (g2 >> 5) & 1023, img = g2 >> 15;
        float4v v;
        #pragma unroll
        for (int j = 0; j < 4; j++)
            v[j] = input[((size_t)img * 128 + c4 + j) * HW + px];
        *(float4v*)(cur + ((size_t)img * HW + px) * 128 + c4) = v;
        int pos = ((px >> 5) + 1) * 34 + (px & 31) + 1;
        unsigned short* ap = A2a + ((size_t)img * PADP + pos) * 128 + c4;
        #pragma unroll
        for (int j = 0; j < 4; j++) ap[j] = f2bf(v[j]);
    }
}

// ---------------- implicit-GEMM 3x3 conv, channels-last, no LDS ----------------
// grid (16 y-blocks, 24 img, 2 zc). Block 256 = 4 waves, wave grid 2m x 2n.
// Block tile 64px(2 rows) x 64co. Wave tile: 2 m-frags(16px) x 2 n-frags(16co).
// 768 blocks = 12 waves/CU (2x round-1) for latency hiding; prefetch depth 4.
template<bool GROUPED, bool RELU, bool RES, bool EF32, bool EA2, bool STAT>
__global__ __launch_bounds__(256, 4) void k_conv(
    const unsigned short* __restrict__ a2in, const unsigned short* __restrict__ w2,
    const float* __restrict__ bias, const float* __restrict__ res,
    float* __restrict__ outf, unsigned short* __restrict__ outa2,
    float* __restrict__ pstat)
{
    const int y0 = blockIdx.x * 2;              // two 32-px rows per block
    const int img = blockIdx.y;
    const int zc = blockIdx.z;
    const int t = threadIdx.x;
    const int wave = t >> 6, lane = t & 63;
    const int wm = wave & 1, wn = wave >> 1;
    const int n16 = lane & 15, quad = lane >> 4;
    const int cog = zc * 64 + wn * 32;          // wave's co base (one 32-co group)
    const int head = zc * 2 + wn;               // co group (grouped head / GN group)

    const short8* w8 = reinterpret_cast<const short8*>(w2);
    const unsigned short* abase = a2in + (size_t)img * A2IMG + (GROUPED ? head * 32 : 0);

    constexpr int NK = GROUPED ? 9 : 36;
    constexpr int D = 4;                        // prefetch depth

    // k-invariant per-lane offsets (elements)
    const int y = y0 + wm;
    int aoff[2];
    #pragma unroll
    for (int mt = 0; mt < 2; mt++)
        aoff[mt] = (y * 34 + mt * 16 + n16) * 128 + quad * 8;
    const int boff = quad * 128 + cog + n16;    // short8-element index

    float4v acc[2][2];
    #pragma unroll
    for (int a = 0; a < 2; a++)
        #pragma unroll
        for (int b = 0; b < 2; b++) acc[a][b] = (float4v){0.f,0.f,0.f,0.f};

    short8 af[D][2], bf[D][2];

    auto loadA = [&](int k, int s){
        const int tap = GROUPED ? k : (k >> 2);
        const int cc  = GROUPED ? 0 : (k & 3);
        const int ky = tap / 3, kx = tap - ky * 3;
        const unsigned short* ab = abase + (ky * 34 + kx) * 128 + cc * 32; // uniform
        #pragma unroll
        for (int mt = 0; mt < 2; mt++)
            af[s][mt] = *reinterpret_cast<const short8*>(ab + aoff[mt]);
    };
    auto loadB = [&](int k, int s){
        const short8* wk = w8 + k * 512;                                  // uniform
        #pragma unroll
        for (int nt = 0; nt < 2; nt++)
            bf[s][nt] = wk[boff + nt * 16];
    };

    #pragma unroll
    for (int k = 0; k < D; k++) { loadA(k, k); loadB(k, k); }
    #pragma unroll
    for (int k = 0; k < NK; k++) {
        const int s = k & (D - 1);
        #pragma unroll
        for (int mt = 0; mt < 2; mt++)
            #pragma unroll
            for (int nt = 0; nt < 2; nt++)
                acc[mt][nt] = __builtin_amdgcn_mfma_f32_16x16x32_bf16(
                    af[s][mt], bf[s][nt], acc[mt][nt], 0, 0, 0);
        if (k + D < NK) { loadA(k + D, s); loadB(k + D, s); }
    }

    // epilogue: D col = n16 (co offset), row = quad*4+reg (x offset)
    float s1 = 0.f, s2 = 0.f;
    #pragma unroll
    for (int mt = 0; mt < 2; mt++) {
        int xb = mt * 16 + quad * 4;
        #pragma unroll
        for (int nt = 0; nt < 2; nt++) {
            int co = cog + nt * 16 + n16;
            float bb = bias[co];
            #pragma unroll
            for (int r = 0; r < 4; r++) {
                int px = y * 32 + xb + r;
                float val = acc[mt][nt][r] + bb;
                if (RELU) val = fmaxf(val, 0.f);
                size_t ci = ((size_t)img * HW + px) * 128 + co;
                if (RES) val += res[ci];
                if (EF32) outf[ci] = val;
                if (EA2) {
                    int pos = (y + 1) * 34 + xb + r + 1;
                    outa2[((size_t)img * PADP + pos) * 128 + co] = f2bf(val);
                }
                if (STAT) { s1 += val; s2 += val * val; }
            }
        }
    }
    if (STAT) {
        #pragma unroll
        for (int o = 32; o > 0; o >>= 1) {
            s1 += __shfl_down(s1, o); s2 += __shfl_down(s2, o);
        }
        if (lane == 0) {
            atomicAdd(&pstat[(img * 4 + head) * 2], s1);
            atomicAdd(&pstat[(img * 4 + head) * 2 + 1], s2);
        }
    }
}

// ---------------- attention logit conv (reads padded bf16 A2v) ----------------
__global__ __launch_bounds__(256) void k_attn(
    const unsigned short* __restrict__ a2v, const float* __restrict__ aw,
    float* __restrict__ ak, float* __restrict__ pstat)
{
    const int img = blockIdx.x;            // b*12 + l
    const int h = blockIdx.y;
    const int y0 = blockIdx.z * 8;
    const int t = threadIdx.x;
    const int b = img / 12, l = img - b * 12;

    if (blockIdx.x == 0 && blockIdx.y == 0 && blockIdx.z == 0 && t < 192)
        pstat[t] = 0.f;                     // zero GN stats for this layer's ff2

    __shared__ float sxv[32 * 341];         // ci-major, pos stride 341
    __shared__ float spos[32];
    if (t < 32) {
        int j2 = t & ~1;
        float freq = __expf(-(float)j2 * 0.28782313662425576f);
        float ang = (float)l * freq;
        spos[t] = (t & 1) ? __cosf(ang) : __sinf(ang);
    }
    __syncthreads();

    // stage 10 padded rows x 34 cols x 32 ci, add pos on interior
    const unsigned short* vb = a2v + (size_t)img * A2IMG + h * 32;
    for (int idx = t; idx < 1360; idx += 256) {
        int q = idx & 3, pos = idx >> 2;
        int ppos = y0 * 34 + pos;
        int row = y0 + pos / 34, col = pos - (pos / 34) * 34;
        bool inter = (row >= 1 && row <= 32 && col >= 1 && col <= 32);
        short8 vv = *reinterpret_cast<const short8*>(vb + (size_t)ppos * 128 + q * 8);
        #pragma unroll
        for (int j = 0; j < 8; j++) {
            float f = bf2f((unsigned short)vv[j]);
            if (inter) f += spos[q * 8 + j];
            sxv[(q * 8 + j) * 341 + pos] = f;
        }
    }
    __syncthreads();

    const float* wb = aw + (h * 64 + 32) * 9;   // K-half weights (uniform -> s_load)
    const int r = t >> 5, xx = t & 31;
    float acc = 0.f;
    #pragma unroll 4
    for (int ci = 0; ci < 32; ci++) {
        #pragma unroll
        for (int ky = 0; ky < 3; ky++)
            #pragma unroll
            for (int kx = 0; kx < 3; kx++)
                acc = fmaf(sxv[ci * 341 + (r + ky) * 34 + xx + kx],
                           wb[ci * 9 + ky * 3 + kx], acc);
    }
    ak[((b * 4 + h) * 12 + l) * HW + (y0 + r) * 32 + xx] = acc;
}

// ---------------- fused softmax + weighted sum + residual (+A2a emit) ----------------
__global__ __launch_bounds__(256) void k_wsum(const float* __restrict__ ak,
    const float* __restrict__ v, float* __restrict__ cur,
    unsigned short* __restrict__ a2a)
{
    int gid = blockIdx.x * 256 + threadIdx.x;   // 2*1024*32
    int c4 = (gid & 31) * 4, px = (gid >> 5) & 1023, b = gid >> 15;
    int h = c4 >> 5;
    const float* wp = ak + ((b * 4 + h) * 12) * HW + px;
    float a[12], m = -1e30f;
    #pragma unroll
    for (int l = 0; l < 12; l++) { a[l] = wp[l * HW]; m = fmaxf(m, a[l]); }
    float ssum = 0.f;
    #pragma unroll
    for (int l = 0; l < 12; l++) { a[l] = __expf(a[l] - m); ssum += a[l]; }
    float invs = 1.f / ssum;
    float4v s = (float4v){0.f,0.f,0.f,0.f};
    #pragma unroll
    for (int l = 0; l < 12; l++) {
        float4v vv = *(const float4v*)(v + (((size_t)(b * 12 + l) * HW) + px) * 128 + c4);
        #pragma unroll
        for (int j = 0; j < 4; j++) s[j] += a[l] * vv[j];
    }
    #pragma unroll
    for (int j = 0; j < 4; j++) s[j] *= invs;
    int pos = ((px >> 5) + 1) * 34 + (px & 31) + 1;
    #pragma unroll
    for (int l = 0; l < 12; l++) {
        size_t ci = (((size_t)(b * 12 + l) * HW) + px) * 128 + c4;
        float4v cv = *(float4v*)(cur + ci);
        #pragma unroll
        for (int j = 0; j < 4; j++) cv[j] += s[j];
        *(float4v*)(cur + ci) = cv;
        unsigned short* ap = a2a + ((size_t)(b * 12 + l) * PADP + pos) * 128 + c4;
        #pragma unroll
        for (int j = 0; j < 4; j++) ap[j] = f2bf(cv[j]);
    }
}

// ---------------- GroupNorm finalize+apply (in-place on cur / final NCHW) ----------------
template<bool LAST>
__global__ __launch_bounds__(256) void k_gnapply(const float* __restrict__ y,
    const float* __restrict__ pstat, const float* __restrict__ gw,
    const float* __restrict__ gb, float* __restrict__ cur,
    unsigned short* __restrict__ a2a, float* __restrict__ outp)
{
    int gid = blockIdx.x * 256 + threadIdx.x;   // 24*1024*32
    if (!LAST) {
        int c4 = (gid & 31) * 4, px = (gid >> 5) & 1023, img = gid >> 15;
        int g = c4 >> 5;
        float S = pstat[(img * 4 + g) * 2], Q = pstat[(img * 4 + g) * 2 + 1];
        float mu = S * (1.f / 32768.f);
        float inv = rsqrtf(Q * (1.f / 32768.f) - mu * mu + 1e-5f);
        float4v vv = *(const float4v*)(y + ((size_t)img * HW + px) * 128 + c4);
        int pos = ((px >> 5) + 1) * 34 + (px & 31) + 1;
        size_t ci = ((size_t)img * HW + px) * 128 + c4;
        unsigned short* ap = a2a + ((size_t)img * PADP + pos) * 128 + c4;
        #pragma unroll
        for (int j = 0; j < 4; j++) {
            float val = (vv[j] - mu) * inv * gw[c4 + j] + gb[c4 + j];
            vv[j] = val;
            ap[j] = f2bf(val);
        }
        *(float4v*)(cur + ci) = vv;
    } else {
        int px4 = (gid & 255) * 4, c = (gid >> 8) & 127, img = gid >> 15;
        int g = c >> 5;
        float S = pstat[(img * 4 + g) * 2], Q = pstat[(img * 4 + g) * 2 + 1];
        float mu = S * (1.f / 32768.f);
        float inv = rsqrtf(Q * (1.f / 32768.f) - mu * mu + 1e-5f);
        float gg = gw[c], bb = gb[c];
        float4v o;
        #pragma unroll
        for (int j = 0; j < 4; j++) {
            float val = y[((size_t)img * HW + px4 + j) * 128 + c];
            o[j] = (val - mu) * inv * gg + bb;
        }
        *(float4v*)(outp + ((size_t)img * 128 + c) * HW + px4) = o;
    }
}

extern "C" void kernel_launch(void* const* d_in, const int* in_sizes, int n_in,
                              void* d_out, int out_size, void* d_ws, size_t ws_size,
                              hipStream_t stream)
{
    const float* input = (const float*)d_in[0];
    // d_in[1] q_w, d_in[2] q_b, d_in[6] att_b cancel in key-axis softmax.
    const float* kv_w  = (const float*)d_in[3];
    const float* kv_b  = (const float*)d_in[4];
    const float* att_w = (const float*)d_in[5];
    const float* ff1_w = (const float*)d_in[7];
    const float* ff1_b = (const float*)d_in[8];
    const float* ff2_w = (const float*)d_in[9];
    const float* ff2_b = (const float*)d_in[10];
    const float* gn_w  = (const float*)d_in[11];
    const float* gn_b  = (const float*)d_in[12];

    // ws layout (~30.5 MB): no buffer aliases another live buffer.
    float* ws  = (float*)d_ws;
    float* cur = ws;                          // CL fp32 (24,1024,128)
    float* ak  = ws + (size_t)NELEM;          // 98304
    float* pstat = ak + 98304;                // 192
    unsigned short* W2d  = (unsigned short*)(pstat + 192);   // 1,474,560
    unsigned short* W2kv = W2d + 1474560;                    // 184,320
    unsigned short* A2v  = W2kv + 184320;                    // 24*147968
    unsigned short* A2a  = A2v + (size_t)IMG * A2IMG;        // 24*147968
    // d_out doubles as the fp32 v buffer (dead before the final output write).
    float* v    = (float*)d_out;
    float* outp = (float*)d_out;

    k_prep<<<12720, 256, 0, stream>>>(ff1_w, ff2_w, kv_w, input,
                                      W2d, W2kv, A2a, A2v, cur);

    for (int li = 0; li < 5; li++) {
        // v (d_out) = grouped conv(A2a) + kv_b ; also emit A2v bf16
        k_conv<true, false, false, true, true, false><<<dim3(16, IMG, 2), 256, 0, stream>>>(
            A2a, W2kv + (size_t)li * 36864, kv_b + li * 128, nullptr, v, A2v, nullptr);
        // attention logits from k = v + pos (also zeroes pstat for this layer)
        k_attn<<<dim3(IMG, 4, 4), 256, 0, stream>>>(A2v, att_w + (size_t)li * 2304, ak, pstat);
        // cur += softmax-weighted sum of v (broadcast over frames); emit A2a
        k_wsum<<<256, 256, 0, stream>>>(ak, v, cur, A2a);
        // f1 = relu(conv(A2a, ff1)) -> A2v only
        k_conv<false, true, false, false, true, false><<<dim3(16, IMG, 2), 256, 0, stream>>>(
            A2a, W2d + (size_t)(li * 2 + 0) * 147456, ff1_b + li * 128, nullptr, nullptr, A2v, nullptr);
        // cur = conv(A2v, ff2) + cur  (in-place, element-wise) + GN partial stats
        k_conv<false, false, true, true, false, true><<<dim3(16, IMG, 2), 256, 0, stream>>>(
            A2v, W2d + (size_t)(li * 2 + 1) * 147456, ff2_b + li * 128, cur, cur, nullptr, pstat);
        // GN apply: in-place on cur + A2a emit, or final NCHW transpose to d_out
        if (li == 4)
            k_gnapply<true><<<3072, 256, 0, stream>>>(cur, pstat, gn_w + li * 128,
                gn_b + li * 128, nullptr, nullptr, outp);
        else
            k_gnapply<false><<<3072, 256, 0, stream>>>(cur, pstat, gn_w + li * 128,
                gn_b + li * 128, cur, A2a, nullptr);
    }
}

// Round 3
// 514.773 us; speedup vs baseline: 1.3963x; 1.3653x over previous
//
#include <hip/hip_runtime.h>

// B=2, T=12, C=128, H=W=32, heads=4, dh=32, layers=5. fp32 I/O.
// Algebra: key-axis softmax cancels q-conv & att_b; attention weights are
// query-independent (head output broadcast over the 12 frames).
// Layout: channels-last fp32 activations [img][1024px][128c] + padded bf16
// copies A2[img][34*34 pos][128c].
// Round 3: convs were serialized on global-load latency (compiler collapsed
// prefetch: VGPR=32, MfmaUtil 5%, occupancy-doubling no-op). Restructured:
// per-block LDS staging of the A-slab (3 padded rows x 34 px x 128 ch, staged
// once, 9x tap reuse, stride padded to 136 shorts for aligned conflict-free
// b128), B weights prefetched per-tap (8 loads covered by a tap of MFMAs).
// Block 256thr = 4 waves, tile 32px x 128co, grid (32,24) = 3 blocks/CU.
#define NELEM 3145728
#define IMG 24
#define CH 128
#define HW 1024
#define PADP 1156          // 34*34
#define A2IMG 147968       // 1156*128

using short8  = __attribute__((ext_vector_type(8))) short;
using float4v = __attribute__((ext_vector_type(4))) float;

__device__ inline unsigned short f2bf(float f){
    union { float f; unsigned u; } c; c.f = f;
    return (unsigned short)((c.u + 0x7FFF + ((c.u >> 16) & 1)) >> 16);
}
__device__ inline float bf2f(unsigned short h){
    union { unsigned u; float f; } c; c.u = ((unsigned)h) << 16; return c.f;
}

// ---------------- fused prep: weight transforms + A2 borders + init ----------------
__global__ __launch_bounds__(256) void k_prep(
    const float* __restrict__ ff1w, const float* __restrict__ ff2w,
    const float* __restrict__ kvw, const float* __restrict__ input,
    unsigned short* __restrict__ Wd, unsigned short* __restrict__ Wkv,
    unsigned short* __restrict__ A2a, unsigned short* __restrict__ A2v,
    float* __restrict__ cur)
{
    int gid = blockIdx.x * 256 + threadIdx.x;        // 12720*256 = 3256320 exact
    if (gid < 1474560) {
        int idx = gid;
        int li2 = idx / 147456, r1 = idx - li2 * 147456;
        int j = r1 & 7, t16 = r1 >> 3;
        int co = t16 & 127, tcq = t16 >> 7;
        int quad = tcq & 3, cc = (tcq >> 2) & 3, tap = tcq >> 4;
        const float* base = ((li2 & 1) ? ff2w : ff1w) + (size_t)(li2 >> 1) * 147456;
        Wd[idx] = f2bf(base[(co * 128 + cc * 32 + quad * 8 + j) * 9 + tap]);
    } else if (gid < 1658880) {
        int idx = gid - 1474560;
        int li = idx / 36864, r1 = idx - li * 36864;
        int j = r1 & 7, t16 = r1 >> 3;
        int co = t16 & 127, tq = t16 >> 7;
        int quad = tq & 3, tap = tq >> 2;
        int h = co >> 5, col = co & 31;
        Wkv[idx] = f2bf(kvw[(size_t)(((li * 4 + h) * 32 + col) * 32 + quad * 8 + j) * 9 + tap]);
    } else if (gid < 2469888) {
        int g2 = gid - 1658880;                      // 2*24*132*128
        int c = g2 & 127, r = g2 >> 7;
        int bp = r % 132, r2 = r / 132;
        int img = r2 % 24, buf = r2 / 24;
        int pos;
        if (bp < 34) pos = bp;
        else if (bp < 68) pos = 33 * 34 + (bp - 34);
        else if (bp < 100) pos = (bp - 68 + 1) * 34;
        else pos = (bp - 100 + 1) * 34 + 33;
        unsigned short* p = buf ? A2v : A2a;
        p[(size_t)img * A2IMG + pos * 128 + c] = 0;
    } else {
        int g2 = gid - 2469888;                      // 24*1024*32
        int c4 = (g2 & 31) * 4, px = (g2 >> 5) & 1023, img = g2 >> 15;
        float4v v;
        #pragma unroll
        for (int j = 0; j < 4; j++)
            v[j] = input[((size_t)img * 128 + c4 + j) * HW + px];
        *(float4v*)(cur + ((size_t)img * HW + px) * 128 + c4) = v;
        int pos = ((px >> 5) + 1) * 34 + (px & 31) + 1;
        unsigned short* ap = A2a + ((size_t)img * PADP + pos) * 128 + c4;
        #pragma unroll
        for (int j = 0; j < 4; j++) ap[j] = f2bf(v[j]);
    }
}

// ---------------- implicit-GEMM 3x3 conv, LDS-staged A ----------------
// grid (32 y-rows, 24 img). Block 256 = 4 waves; tile 32px x 128co.
// Wave wn owns co group [wn*32, wn*32+32): 2 m-frags(16px) x 2 n-frags(16co).
// A-slab (3 padded rows x 34px x 128ch) staged once to LDS (9x tap reuse);
// px stride padded to 136 shorts => 16B-aligned b128, ~2-way banks (free).
// B: per-tap register prefetch (CCS*2 x short8), one L2 latency per tap.
template<bool GROUPED, bool RELU, bool RES, bool EF32, bool EA2, bool STAT>
__global__ __launch_bounds__(256, 3) void k_conv(
    const unsigned short* __restrict__ a2in, const unsigned short* __restrict__ w2,
    const float* __restrict__ bias, const float* __restrict__ res,
    float* __restrict__ outf, unsigned short* __restrict__ outa2,
    float* __restrict__ pstat)
{
    const int y = blockIdx.x;                   // output row 0..31
    const int img = blockIdx.y;
    const int t = threadIdx.x;
    const int wave = t >> 6, lane = t & 63;
    const int n16 = lane & 15, quad = lane >> 4;
    const int cog = wave * 32;                  // wave's co base
    const int head = wave;                      // grouped head / GN group

    constexpr int CCS = GROUPED ? 1 : 4;        // cc steps per tap

    __shared__ unsigned short sA[102 * 136];    // 27744 B

    // stage: padded rows y..y+2 (contiguous slab), 102px x 16 groups of 8ch
    const unsigned short* slab = a2in + (size_t)img * A2IMG + (size_t)y * 34 * 128;
    #pragma unroll
    for (int it = 0; it < 7; it++) {
        int u = it * 256 + t;
        if (u < 1632) {
            int px = u >> 4, g = u & 15;
            short8 vv = *reinterpret_cast<const short8*>(slab + px * 128 + g * 8);
            *reinterpret_cast<short8*>(sA + px * 136 + g * 8) = vv;
        }
    }

    const short8* w8 = reinterpret_cast<const short8*>(w2);
    const int boff = quad * 128 + cog + n16;    // short8-element index into W

    short8 bfr[2][CCS][2];                      // [tap parity][cc][nt]
    auto loadB = [&](int kbase, int buf){
        #pragma unroll
        for (int cc = 0; cc < CCS; cc++)
            #pragma unroll
            for (int nt = 0; nt < 2; nt++)
                bfr[buf][cc][nt] = w8[(size_t)(kbase + cc) * 512 + boff + nt * 16];
    };
    loadB(0, 0);

    float4v acc[2][2];
    #pragma unroll
    for (int a = 0; a < 2; a++)
        #pragma unroll
        for (int b = 0; b < 2; b++) acc[a][b] = (float4v){0.f,0.f,0.f,0.f};

    __syncthreads();

    const int cibase = GROUPED ? head * 32 : 0; // A ci base (grouped: own head)
    #pragma unroll
    for (int tap = 0; tap < 9; tap++) {
        if (tap + 1 < 9) loadB((tap + 1) * CCS, (tap + 1) & 1);
        const int ky = tap / 3, kx = tap - ky * 3;
        #pragma unroll
        for (int cc = 0; cc < CCS; cc++) {
            short8 af[2];
            #pragma unroll
            for (int mt = 0; mt < 2; mt++) {
                int pxl = ky * 34 + kx + mt * 16 + n16;
                af[mt] = *reinterpret_cast<const short8*>(
                    sA + pxl * 136 + cibase + cc * 32 + quad * 8);
            }
            #pragma unroll
            for (int mt = 0; mt < 2; mt++)
                #pragma unroll
                for (int nt = 0; nt < 2; nt++)
                    acc[mt][nt] = __builtin_amdgcn_mfma_f32_16x16x32_bf16(
                        af[mt], bfr[tap & 1][cc][nt], acc[mt][nt], 0, 0, 0);
        }
    }

    // epilogue: D col = n16 (co offset), row = quad*4+reg (x offset)
    float s1 = 0.f, s2 = 0.f;
    #pragma unroll
    for (int mt = 0; mt < 2; mt++) {
        int xb = mt * 16 + quad * 4;
        #pragma unroll
        for (int nt = 0; nt < 2; nt++) {
            int co = cog + nt * 16 + n16;
            float bb = bias[co];
            #pragma unroll
            for (int r = 0; r < 4; r++) {
                int px = y * 32 + xb + r;
                float val = acc[mt][nt][r] + bb;
                if (RELU) val = fmaxf(val, 0.f);
                size_t ci = ((size_t)img * HW + px) * 128 + co;
                if (RES) val += res[ci];
                if (EF32) outf[ci] = val;
                if (EA2) {
                    int pos = (y + 1) * 34 + xb + r + 1;
                    outa2[((size_t)img * PADP + pos) * 128 + co] = f2bf(val);
                }
                if (STAT) { s1 += val; s2 += val * val; }
            }
        }
    }
    if (STAT) {
        #pragma unroll
        for (int o = 32; o > 0; o >>= 1) {
            s1 += __shfl_down(s1, o); s2 += __shfl_down(s2, o);
        }
        if (lane == 0) {
            atomicAdd(&pstat[(img * 4 + head) * 2], s1);
            atomicAdd(&pstat[(img * 4 + head) * 2 + 1], s2);
        }
    }
}

// ---------------- attention logit conv (reads padded bf16 A2v) ----------------
__global__ __launch_bounds__(256) void k_attn(
    const unsigned short* __restrict__ a2v, const float* __restrict__ aw,
    float* __restrict__ ak, float* __restrict__ pstat)
{
    const int img = blockIdx.x;            // b*12 + l
    const int h = blockIdx.y;
    const int y0 = blockIdx.z * 8;
    const int t = threadIdx.x;
    const int b = img / 12, l = img - b * 12;

    if (blockIdx.x == 0 && blockIdx.y == 0 && blockIdx.z == 0 && t < 192)
        pstat[t] = 0.f;                     // zero GN stats for this layer's ff2

    __shared__ float sxv[32 * 341];         // ci-major, pos stride 341
    __shared__ float spos[32];
    if (t < 32) {
        int j2 = t & ~1;
        float freq = __expf(-(float)j2 * 0.28782313662425576f);
        float ang = (float)l * freq;
        spos[t] = (t & 1) ? __cosf(ang) : __sinf(ang);
    }
    __syncthreads();

    // stage 10 padded rows x 34 cols x 32 ci, add pos on interior
    const unsigned short* vb = a2v + (size_t)img * A2IMG + h * 32;
    for (int idx = t; idx < 1360; idx += 256) {
        int q = idx & 3, pos = idx >> 2;
        int ppos = y0 * 34 + pos;
        int row = y0 + pos / 34, col = pos - (pos / 34) * 34;
        bool inter = (row >= 1 && row <= 32 && col >= 1 && col <= 32);
        short8 vv = *reinterpret_cast<const short8*>(vb + (size_t)ppos * 128 + q * 8);
        #pragma unroll
        for (int j = 0; j < 8; j++) {
            float f = bf2f((unsigned short)vv[j]);
            if (inter) f += spos[q * 8 + j];
            sxv[(q * 8 + j) * 341 + pos] = f;
        }
    }
    __syncthreads();

    const float* wb = aw + (h * 64 + 32) * 9;   // K-half weights (uniform -> s_load)
    const int r = t >> 5, xx = t & 31;
    float acc = 0.f;
    #pragma unroll 4
    for (int ci = 0; ci < 32; ci++) {
        #pragma unroll
        for (int ky = 0; ky < 3; ky++)
            #pragma unroll
            for (int kx = 0; kx < 3; kx++)
                acc = fmaf(sxv[ci * 341 + (r + ky) * 34 + xx + kx],
                           wb[ci * 9 + ky * 3 + kx], acc);
    }
    ak[((b * 4 + h) * 12 + l) * HW + (y0 + r) * 32 + xx] = acc;
}

// ---------------- fused softmax + weighted sum + residual (+A2a emit) ----------------
__global__ __launch_bounds__(256) void k_wsum(const float* __restrict__ ak,
    const float* __restrict__ v, float* __restrict__ cur,
    unsigned short* __restrict__ a2a)
{
    int gid = blockIdx.x * 256 + threadIdx.x;   // 2*1024*32
    int c4 = (gid & 31) * 4, px = (gid >> 5) & 1023, b = gid >> 15;
    int h = c4 >> 5;
    const float* wp = ak + ((b * 4 + h) * 12) * HW + px;
    float a[12], m = -1e30f;
    #pragma unroll
    for (int l = 0; l < 12; l++) { a[l] = wp[l * HW]; m = fmaxf(m, a[l]); }
    float ssum = 0.f;
    #pragma unroll
    for (int l = 0; l < 12; l++) { a[l] = __expf(a[l] - m); ssum += a[l]; }
    float invs = 1.f / ssum;
    float4v s = (float4v){0.f,0.f,0.f,0.f};
    #pragma unroll
    for (int l = 0; l < 12; l++) {
        float4v vv = *(const float4v*)(v + (((size_t)(b * 12 + l) * HW) + px) * 128 + c4);
        #pragma unroll
        for (int j = 0; j < 4; j++) s[j] += a[l] * vv[j];
    }
    #pragma unroll
    for (int j = 0; j < 4; j++) s[j] *= invs;
    int pos = ((px >> 5) + 1) * 34 + (px & 31) + 1;
    #pragma unroll
    for (int l = 0; l < 12; l++) {
        size_t ci = (((size_t)(b * 12 + l) * HW) + px) * 128 + c4;
        float4v cv = *(float4v*)(cur + ci);
        #pragma unroll
        for (int j = 0; j < 4; j++) cv[j] += s[j];
        *(float4v*)(cur + ci) = cv;
        unsigned short* ap = a2a + ((size_t)(b * 12 + l) * PADP + pos) * 128 + c4;
        #pragma unroll
        for (int j = 0; j < 4; j++) ap[j] = f2bf(cv[j]);
    }
}

// ---------------- GroupNorm finalize+apply (in-place on cur / final NCHW) ----------------
template<bool LAST>
__global__ __launch_bounds__(256) void k_gnapply(const float* __restrict__ y,
    const float* __restrict__ pstat, const float* __restrict__ gw,
    const float* __restrict__ gb, float* __restrict__ cur,
    unsigned short* __restrict__ a2a, float* __restrict__ outp)
{
    int gid = blockIdx.x * 256 + threadIdx.x;   // 24*1024*32
    if (!LAST) {
        int c4 = (gid & 31) * 4, px = (gid >> 5) & 1023, img = gid >> 15;
        int g = c4 >> 5;
        float S = pstat[(img * 4 + g) * 2], Q = pstat[(img * 4 + g) * 2 + 1];
        float mu = S * (1.f / 32768.f);
        float inv = rsqrtf(Q * (1.f / 32768.f) - mu * mu + 1e-5f);
        float4v vv = *(const float4v*)(y + ((size_t)img * HW + px) * 128 + c4);
        int pos = ((px >> 5) + 1) * 34 + (px & 31) + 1;
        size_t ci = ((size_t)img * HW + px) * 128 + c4;
        unsigned short* ap = a2a + ((size_t)img * PADP + pos) * 128 + c4;
        #pragma unroll
        for (int j = 0; j < 4; j++) {
            float val = (vv[j] - mu) * inv * gw[c4 + j] + gb[c4 + j];
            vv[j] = val;
            ap[j] = f2bf(val);
        }
        *(float4v*)(cur + ci) = vv;
    } else {
        int px4 = (gid & 255) * 4, c = (gid >> 8) & 127, img = gid >> 15;
        int g = c >> 5;
        float S = pstat[(img * 4 + g) * 2], Q = pstat[(img * 4 + g) * 2 + 1];
        float mu = S * (1.f / 32768.f);
        float inv = rsqrtf(Q * (1.f / 32768.f) - mu * mu + 1e-5f);
        float gg = gw[c], bb = gb[c];
        float4v o;
        #pragma unroll
        for (int j = 0; j < 4; j++) {
            float val = y[((size_t)img * HW + px4 + j) * 128 + c];
            o[j] = (val - mu) * inv * gg + bb;
        }
        *(float4v*)(outp + ((size_t)img * 128 + c) * HW + px4) = o;
    }
}

extern "C" void kernel_launch(void* const* d_in, const int* in_sizes, int n_in,
                              void* d_out, int out_size, void* d_ws, size_t ws_size,
                              hipStream_t stream)
{
    const float* input = (const float*)d_in[0];
    // d_in[1] q_w, d_in[2] q_b, d_in[6] att_b cancel in key-axis softmax.
    const float* kv_w  = (const float*)d_in[3];
    const float* kv_b  = (const float*)d_in[4];
    const float* att_w = (const float*)d_in[5];
    const float* ff1_w = (const float*)d_in[7];
    const float* ff1_b = (const float*)d_in[8];
    const float* ff2_w = (const float*)d_in[9];
    const float* ff2_b = (const float*)d_in[10];
    const float* gn_w  = (const float*)d_in[11];
    const float* gn_b  = (const float*)d_in[12];

    // ws layout (~30.5 MB): no buffer aliases another live buffer.
    float* ws  = (float*)d_ws;
    float* cur = ws;                          // CL fp32 (24,1024,128)
    float* ak  = ws + (size_t)NELEM;          // 98304
    float* pstat = ak + 98304;                // 192
    unsigned short* W2d  = (unsigned short*)(pstat + 192);   // 1,474,560
    unsigned short* W2kv = W2d + 1474560;                    // 184,320
    unsigned short* A2v  = W2kv + 184320;                    // 24*147968
    unsigned short* A2a  = A2v + (size_t)IMG * A2IMG;        // 24*147968
    // d_out doubles as the fp32 v buffer (dead before the final output write).
    float* v    = (float*)d_out;
    float* outp = (float*)d_out;

    k_prep<<<12720, 256, 0, stream>>>(ff1_w, ff2_w, kv_w, input,
                                      W2d, W2kv, A2a, A2v, cur);

    for (int li = 0; li < 5; li++) {
        // v (d_out) = grouped conv(A2a) + kv_b ; also emit A2v bf16
        k_conv<true, false, false, true, true, false><<<dim3(32, IMG), 256, 0, stream>>>(
            A2a, W2kv + (size_t)li * 36864, kv_b + li * 128, nullptr, v, A2v, nullptr);
        // attention logits from k = v + pos (also zeroes pstat for this layer)
        k_attn<<<dim3(IMG, 4, 4), 256, 0, stream>>>(A2v, att_w + (size_t)li * 2304, ak, pstat);
        // cur += softmax-weighted sum of v (broadcast over frames); emit A2a
        k_wsum<<<256, 256, 0, stream>>>(ak, v, cur, A2a);
        // f1 = relu(conv(A2a, ff1)) -> A2v only
        k_conv<false, true, false, false, true, false><<<dim3(32, IMG), 256, 0, stream>>>(
            A2a, W2d + (size_t)(li * 2 + 0) * 147456, ff1_b + li * 128, nullptr, nullptr, A2v, nullptr);
        // cur = conv(A2v, ff2) + cur  (in-place, element-wise) + GN partial stats
        k_conv<false, false, true, true, false, true><<<dim3(32, IMG), 256, 0, stream>>>(
            A2v, W2d + (size_t)(li * 2 + 1) * 147456, ff2_b + li * 128, cur, cur, nullptr, pstat);
        // GN apply: in-place on cur + A2a emit, or final NCHW transpose to d_out
        if (li == 4)
            k_gnapply<true><<<3072, 256, 0, stream>>>(cur, pstat, gn_w + li * 128,
                gn_b + li * 128, nullptr, nullptr, outp);
        else
            k_gnapply<false><<<3072, 256, 0, stream>>>(cur, pstat, gn_w + li * 128,
                gn_b + li * 128, cur, A2a, nullptr);
    }
}